// Round 10
// baseline (134.522 us; speedup 1.0000x reference)
//
#include <hip/hip_runtime.h>
#include <hip/hip_bf16.h>

typedef __attribute__((ext_vector_type(8))) __bf16 bf16x8;
typedef __attribute__((ext_vector_type(4))) float f32x4;

namespace {
constexpr int kB = 8;
constexpr int kT = 2048;
constexpr int kD = 1024;
constexpr int kH = 64;
}

// ---------------------------------------------------------------------------
// Kernel 1: W -> wtf fragment layout [nt][ks][lane][8] bf16. (unchanged)
// ---------------------------------------------------------------------------
__global__ __launch_bounds__(256) void wt_kernel(
    const float* __restrict__ Wq, const float* __restrict__ Wk,
    const float* __restrict__ Wv, __bf16* __restrict__ wtf) {
  const int wid = threadIdx.x >> 6;
  const int lane = threadIdx.x & 63;
  const int lr = lane & 15;
  const int lg = lane >> 4;
  const int p = blockIdx.x * 4 + wid;  // 0..383 = nt*32 + ks
  const int nt = p >> 5;
  const int ks = p & 31;
  const float* W = (nt < 4) ? Wq : ((nt < 8) ? Wk : Wv);
  const float scale = (nt < 4) ? 0.18033688011112042f : 1.0f;
  const int col = (nt & 3) * 16 + lr;
  bf16x8 v;
#pragma unroll
  for (int j = 0; j < 8; ++j)
    v[j] = (__bf16)(W[(size_t)(ks * 32 + lg * 8 + j) * kH + col] * scale);
  *(bf16x8*)(wtf + (size_t)p * 512 + lane * 8) = v;
}

// ---------------------------------------------------------------------------
// Kernel 2: projections, v2. Grid = M/32 = 512 blocks, 4 waves K-split-4.
// CHANGE A: per-wave private staging -- wave w stages x[rows][256w..256w+256)
//   into its own 16KB LDS region and starts MFMA with NO block barrier
//   (wave-local lgkmcnt ordering). Waves overlap HBM-load vs MFMA on the SIMD.
// CHANGE B: epilogue scatter goes to a 12KB LDS image of the exact global
//   layout (Q 4KB | kf chunk-group 4KB | vf chunk-group 4KB), then 3
//   coalesced b128 global stores per thread. No scattered 2B global writes.
// ---------------------------------------------------------------------------
__global__ __launch_bounds__(256, 2) void proj_kernel(
    const float* __restrict__ x, const __bf16* __restrict__ wtf,
    __bf16* __restrict__ Q, __bf16* __restrict__ kf, __bf16* __restrict__ vf) {
  __shared__ alignas(16) char lds_raw[65536];
  // [0,64K): 4 x 16KB per-wave stage | later aliased: [0,48K) p_s, [48K,60K) ostage
  float* p_s = (float*)lds_raw;
  char* ostage = lds_raw + 49152;

  const int tid = threadIdx.x;
  const int wid = tid >> 6;
  const int lane = tid & 63;
  const int lr = lane & 15;
  const int lg = lane >> 4;
  const int row0 = blockIdx.x * 32;

  // ---- per-wave stage: rows 0..31 of this wave's K-quarter, XOR-swizzled ----
  char* wstage = lds_raw + wid * 16384;  // 32 rows x 512B
  {
    const int srow = lane >> 5;          // 0/1: two rows per iteration
    const int scol = (lane & 31) * 8;    // fp32 col within quarter (x8)
    const float* xq = x + (size_t)row0 * kD + wid * 256;
#pragma unroll
    for (int i = 0; i < 16; ++i) {
      const int row = i * 2 + srow;
      const float* src = xq + (size_t)row * kD + scol;
      const float4 a = ((const float4*)src)[0];
      const float4 b = ((const float4*)src)[1];
      bf16x8 v;
      v[0] = (__bf16)a.x; v[1] = (__bf16)a.y; v[2] = (__bf16)a.z; v[3] = (__bf16)a.w;
      v[4] = (__bf16)b.x; v[5] = (__bf16)b.y; v[6] = (__bf16)b.z; v[7] = (__bf16)b.w;
      const int byte = row * 512 + ((scol * 2) ^ ((row & 7) << 4));
      *(bf16x8*)(wstage + byte) = v;
    }
  }
  // no __syncthreads: wave reads only its own region (lgkmcnt ordering)

  f32x4 acc[2][12];
#pragma unroll
  for (int a = 0; a < 2; ++a)
#pragma unroll
    for (int nt = 0; nt < 12; ++nt) acc[a][nt] = (f32x4)(0.0f);

  const int swz = (lr & 7) << 4;
#pragma unroll 2
  for (int i = 0; i < 8; ++i) {
    const int kb = lg * 16 + i * 64;  // byte offset within 512B row
    const bf16x8 a0 = *(const bf16x8*)(wstage + lr * 512 + (kb ^ swz));
    const bf16x8 a1 = *(const bf16x8*)(wstage + (16 + lr) * 512 + (kb ^ swz));
#pragma unroll
    for (int nt = 0; nt < 12; ++nt) {
      const bf16x8 bfrag =
          *(const bf16x8*)(wtf + (size_t)(nt * 32 + wid * 8 + i) * 512 + lane * 8);
      acc[0][nt] = __builtin_amdgcn_mfma_f32_16x16x32_bf16(a0, bfrag, acc[0][nt], 0, 0, 0);
      acc[1][nt] = __builtin_amdgcn_mfma_f32_16x16x32_bf16(a1, bfrag, acc[1][nt], 0, 0, 0);
    }
  }

  // ---- reduce 4 K-quarters; 2 phases; results scattered into LDS ostage ----
  const int col = tid & 15;
  const int rowq = tid >> 4;
#pragma unroll
  for (int p = 0; p < 2; ++p) {
    __syncthreads();  // all waves done with stage regions / previous phase
#pragma unroll
    for (int j = 0; j < 12; ++j)
      *(f32x4*)&p_s[((wid * 12 + j) * 64 + lane) * 4] = acc[p][j];
    __syncthreads();
    const int tl = p * 16 + rowq;  // block-local t (0..31)
#pragma unroll
    for (int j = 0; j < 12; ++j) {
      const int base = ((j * 64 + (rowq >> 2) * 16 + col) << 2) | (rowq & 3);
      const float v =
          p_s[base] + p_s[base + 3072] + p_s[base + 6144] + p_s[base + 9216];
      if (j < 4) {
        ((__bf16*)ostage)[tl * 64 + j * 16 + col] = (__bf16)v;
      } else if (j < 8) {
        const int h = (j - 4) * 16 + col;
        const int lrk = ((tl >> 3) << 2) | (tl & 3);
        const int sub = (tl >> 2) & 1;
        const int dh = h >> 5;
        const int lgk = (h & 31) >> 3;
        const int jj = h & 7;
        ((__bf16*)(ostage + 4096))[(sub * 2 + dh) * 512 + (lgk * 16 + lrk) * 8 + jj] =
            (__bf16)v;
      } else {
        ((__bf16*)(ostage + 8192))[(j - 8) * 512 + (tl >> 3) * 128 + col * 8 +
                                   (tl & 7)] = (__bf16)v;
      }
    }
  }
  __syncthreads();

  // ---- coalesced copy: 12KB LDS image -> global (3 b128 stores/thread) ----
  const int b = row0 >> 11;
  const int tc = (row0 & 2047) >> 5;  // t-chunk-group
  const size_t cbase = ((size_t)b * 64 + tc) * 2048;
  *(bf16x8*)(Q + (size_t)row0 * kH + tid * 8) =
      *(const bf16x8*)(ostage + tid * 16);
  *(bf16x8*)(kf + cbase + tid * 8) = *(const bf16x8*)(ostage + 4096 + tid * 16);
  *(bf16x8*)(vf + cbase + tid * 8) = *(const bf16x8*)(ostage + 8192 + tid * 16);
}

// ---------------------------------------------------------------------------
// Kernel 3: causal flash attention (UNCHANGED this round for attribution).
// ---------------------------------------------------------------------------
__global__ __launch_bounds__(256, 4) void attn_kernel(
    const __bf16* __restrict__ Q, const __bf16* __restrict__ kf,
    const __bf16* __restrict__ vf, float* __restrict__ out) {
  __shared__ alignas(16) float o_s[4][16][68];
  __shared__ float m_s[4][16], l_s[4][4][16];  // [wave][lg][q]

  const int wid = threadIdx.x >> 6;
  const int lane = threadIdx.x & 63;
  const int lr = lane & 15;
  const int lg = lane >> 4;
  const int b = blockIdx.y;
  const int qt = (int)gridDim.x - 1 - (int)blockIdx.x;  // long tiles first
  const int q0 = qt * 16;

  const __bf16* Qb = Q + (size_t)b * kT * kH;
  const __bf16* Kf = kf + (size_t)b * 131072 + lane * 8;
  const __bf16* Vf = vf + (size_t)b * 131072 + lane * 8;

  const bf16x8 aq0 = *(const bf16x8*)(Qb + (size_t)(q0 + lr) * kH + lg * 8);
  const bf16x8 aq1 = *(const bf16x8*)(Qb + (size_t)(q0 + lr) * kH + 32 + lg * 8);

  f32x4 o[4];
#pragma unroll
  for (int i = 0; i < 4; ++i) o[i] = (f32x4)(0.0f);
  float m = -1e30f, l = 0.0f;  // l is a PER-LANE partial (this lane's keys)

  const int ntiles = (q0 + 16 + 31) >> 5;

  bf16x8 ka[4], va[4];
  {
    const int t0c = (wid < ntiles) ? wid : 0;
#pragma unroll
    for (int c = 0; c < 4; ++c) {
      ka[c] = *(const bf16x8*)(Kf + ((size_t)t0c * 4 + c) * 512);
      va[c] = *(const bf16x8*)(Vf + ((size_t)t0c * 4 + c) * 512);
    }
  }

  for (int t = wid; t < ntiles; t += 4) {
    const int tn = (t + 4 < ntiles) ? (t + 4) : t;
    bf16x8 kn[4], vn[4];
#pragma unroll
    for (int c = 0; c < 4; ++c) {
      kn[c] = *(const bf16x8*)(Kf + ((size_t)tn * 4 + c) * 512);
      vn[c] = *(const bf16x8*)(Vf + ((size_t)tn * 4 + c) * 512);
    }

    const int kv = t * 32;
    f32x4 s0 = (f32x4)(0.0f), s1 = (f32x4)(0.0f);
    s0 = __builtin_amdgcn_mfma_f32_16x16x32_bf16(ka[0], aq0, s0, 0, 0, 0);
    s0 = __builtin_amdgcn_mfma_f32_16x16x32_bf16(ka[1], aq1, s0, 0, 0, 0);
    s1 = __builtin_amdgcn_mfma_f32_16x16x32_bf16(ka[2], aq0, s1, 0, 0, 0);
    s1 = __builtin_amdgcn_mfma_f32_16x16x32_bf16(ka[3], aq1, s1, 0, 0, 0);

    if (kv + 31 > q0) {
      const int q = q0 + lr;
#pragma unroll
      for (int r = 0; r < 4; ++r) {
        if (kv + 8 * lg + r > q) s0[r] = -1e30f;
        if (kv + 8 * lg + 4 + r > q) s1[r] = -1e30f;
      }
    }

    const float pm = fmaxf(fmaxf(fmaxf(s0[0], s0[1]), fmaxf(s0[2], s0[3])),
                           fmaxf(fmaxf(s1[0], s1[1]), fmaxf(s1[2], s1[3])));
    if (!__all(pm - m <= 8.0f)) {
      float t2 = fmaxf(pm, __shfl_xor(pm, 16, 64));
      t2 = fmaxf(t2, __shfl_xor(t2, 32, 64));
      const float mn = fmaxf(m, t2);
      const float alpha = exp2f(m - mn);
#pragma unroll
      for (int ht = 0; ht < 4; ++ht) o[ht] = o[ht] * alpha;
      l *= alpha;
      m = mn;
    }

    float sum = 0.0f;
    bf16x8 pb;
#pragma unroll
    for (int r = 0; r < 4; ++r) {
      const float p0 = exp2f(s0[r] - m);
      const float p1 = exp2f(s1[r] - m);
      sum += p0 + p1;
      pb[r] = (__bf16)p0;
      pb[r + 4] = (__bf16)p1;
    }
    l += sum;

#pragma unroll
    for (int ht = 0; ht < 4; ++ht)
      o[ht] = __builtin_amdgcn_mfma_f32_16x16x32_bf16(va[ht], pb, o[ht], 0, 0, 0);

#pragma unroll
    for (int c = 0; c < 4; ++c) {
      ka[c] = kn[c];
      va[c] = vn[c];
    }
  }

#pragma unroll
  for (int ht = 0; ht < 4; ++ht)
    *(f32x4*)&o_s[wid][lr][ht * 16 + lg * 4] = o[ht];
  if (lg == 0) m_s[wid][lr] = m;
  l_s[wid][lg][lr] = l;
  __syncthreads();

  const int ti = threadIdx.x;
  const int q = ti & 15;
  const int hb = ti >> 4;
  float mm = fmaxf(fmaxf(m_s[0][q], m_s[1][q]), fmaxf(m_s[2][q], m_s[3][q]));
  f32x4 acc = (f32x4)(0.0f);
  float ll = 0.0f;
#pragma unroll
  for (int w = 0; w < 4; ++w) {
    const float sc = exp2f(m_s[w][q] - mm);
    const float lw =
        l_s[w][0][q] + l_s[w][1][q] + l_s[w][2][q] + l_s[w][3][q];
    ll += sc * lw;
    const f32x4 ov = *(const f32x4*)&o_s[w][q][hb * 4];
    acc += ov * sc;
  }
  const float inv = 1.0f / ll;
  *(f32x4*)(out + ((size_t)b * kT + q0 + q) * kH + hb * 4) = acc * inv;
}

// ---------------------------------------------------------------------------
extern "C" void kernel_launch(void* const* d_in, const int* in_sizes, int n_in,
                              void* d_out, int out_size, void* d_ws, size_t ws_size,
                              hipStream_t stream) {
  (void)in_sizes; (void)n_in; (void)out_size; (void)ws_size;
  const float* x  = (const float*)d_in[0];
  const float* Wq = (const float*)d_in[1];
  const float* Wk = (const float*)d_in[2];
  const float* Wv = (const float*)d_in[3];
  float* out = (float*)d_out;

  char* ws = (char*)d_ws;
  // workspace layout (bytes):
  //   wtf : 384*512*2 = 393216
  //   Q   : 2097152
  //   kf  : 2097152
  //   vf  : 2097152
  __bf16* wtf = (__bf16*)(ws);
  __bf16* Qp  = (__bf16*)(ws + 393216);
  __bf16* kfp = (__bf16*)(ws + 393216 + 2097152);
  __bf16* vfp = (__bf16*)(ws + 393216 + 2 * 2097152);

  wt_kernel<<<96, 256, 0, stream>>>(Wq, Wk, Wv, wtf);
  proj_kernel<<<kB * kT / 32, 256, 0, stream>>>(x, wtf, Qp, kfp, vfp);
  attn_kernel<<<dim3(kT / 16, kB), 256, 0, stream>>>(Qp, kfp, vfp, out);
}